// Round 1
// baseline (392.364 us; speedup 1.0000x reference)
//
#include <hip/hip_runtime.h>
#include <math.h>

#define EPS 1e-7f
#define FN_PENALTY 10.0f

__device__ __forceinline__ float waveReduceSum(float v) {
    // wave = 64 lanes on gfx950
    #pragma unroll
    for (int off = 32; off > 0; off >>= 1)
        v += __shfl_down(v, off, 64);
    return v;
}

__device__ __forceinline__ float4 validate_fix(float4 b) {
    bool invalid = (b.x > b.z) || (b.y > b.w);
    if (invalid) {
        b.x = fmaxf(b.x, 0.0f);
        b.y = fmaxf(b.y, 0.0f);
        b.z = fmaxf(b.z, 0.0f);
        b.w = fmaxf(b.w, 0.0f);
    }
    b.z = fmaxf(b.z, b.x + 1e-6f);
    b.w = fmaxf(b.w, b.y + 1e-6f);
    return b;
}

__global__ __launch_bounds__(256) void loss_reduce(
    const float4* __restrict__ pred_logits,
    const int*    __restrict__ labels,
    const float4* __restrict__ pred_boxes,
    const float4* __restrict__ target_boxes,
    const float*  __restrict__ cut_logits,
    const float*  __restrict__ cut_targets,
    float* __restrict__ ws, int n)
{
    float s_class = 0.0f, s_bbox = 0.0f, s_giou = 0.0f, s_cut = 0.0f;
    const int stride = gridDim.x * blockDim.x;
    for (int i = blockIdx.x * blockDim.x + threadIdx.x; i < n; i += stride) {
        // ---- focal class loss ----
        float4 lg = pred_logits[i];
        int lbl = labels[i] & 3;
        float l0 = lg.x, l1 = lg.y, l2 = lg.z, l3 = lg.w;
        float m = fmaxf(fmaxf(l0, l1), fmaxf(l2, l3));
        float se = expf(l0 - m) + expf(l1 - m) + expf(l2 - m) + expf(l3 - m);
        float lse = m + logf(se);
        float lsel = (lbl == 0) ? l0 : (lbl == 1) ? l1 : (lbl == 2) ? l2 : l3;
        float ce = lse - lsel;
        float pt = expf(-ce);
        float om = 1.0f - pt;
        s_class += om * om * ce;   // ALPHA=1, GAMMA=2

        // ---- bbox L1 ----
        float4 pb = pred_boxes[i];
        float4 tb = target_boxes[i];
        s_bbox += fabsf(pb.x - tb.x) + fabsf(pb.y - tb.y)
                + fabsf(pb.z - tb.z) + fabsf(pb.w - tb.w);

        // ---- GIoU ----
        float4 b1 = validate_fix(pb);
        float4 b2 = validate_fix(tb);
        float area1 = (b1.z - b1.x) * (b1.w - b1.y);
        float area2 = (b2.z - b2.x) * (b2.w - b2.y);
        float ltx = fmaxf(b1.x, b2.x), lty = fmaxf(b1.y, b2.y);
        float rbx = fminf(b1.z, b2.z), rby = fminf(b1.w, b2.w);
        float iw = fmaxf(rbx - ltx, 0.0f), ih = fmaxf(rby - lty, 0.0f);
        float inter = iw * ih;
        float uni = area1 + area2 - inter;
        float iou = inter / (uni + EPS);
        float ex1 = fminf(b1.x, b2.x), ey1 = fminf(b1.y, b2.y);
        float ex2 = fmaxf(b1.z, b2.z), ey2 = fmaxf(b1.w, b2.w);
        float ew = fmaxf(ex2 - ex1, 0.0f), eh = fmaxf(ey2 - ey1, 0.0f);
        float enc = ew * eh;
        float giou = iou - (enc - uni) / (enc + EPS);
        s_giou += fmaxf(1.0f - giou, 0.0f);

        // ---- weighted BCE ----
        float cl = cut_logits[i];
        float ct = cut_targets[i];
        float bce = fmaxf(cl, 0.0f) - cl * ct + log1pf(expf(-fabsf(cl)));
        float prob = 1.0f / (1.0f + expf(-cl));
        float w = ((ct == 1.0f) && (prob < 0.5f)) ? FN_PENALTY : 1.0f;
        s_cut += bce * w;
    }

    // ---- block reduction: wave shuffle, then LDS across the 4 waves ----
    s_class = waveReduceSum(s_class);
    s_bbox  = waveReduceSum(s_bbox);
    s_giou  = waveReduceSum(s_giou);
    s_cut   = waveReduceSum(s_cut);

    __shared__ float red[4][4];  // [wave][loss-term]
    const int lane = threadIdx.x & 63;
    const int wave = threadIdx.x >> 6;
    if (lane == 0) {
        red[wave][0] = s_class;
        red[wave][1] = s_bbox;
        red[wave][2] = s_giou;
        red[wave][3] = s_cut;
    }
    __syncthreads();
    if (threadIdx.x == 0) {
        float c = 0.0f, b = 0.0f, g = 0.0f, u = 0.0f;
        #pragma unroll
        for (int w = 0; w < 4; ++w) {
            c += red[w][0]; b += red[w][1]; g += red[w][2]; u += red[w][3];
        }
        atomicAdd(&ws[0], c);
        atomicAdd(&ws[1], b);
        atomicAdd(&ws[2], g);
        atomicAdd(&ws[3], u);
    }
}

__global__ void finalize_kernel(const float* __restrict__ ws,
                                float* __restrict__ out, float inv_n)
{
    if (threadIdx.x == 0 && blockIdx.x == 0) {
        float lc   = fmaxf(ws[0] * inv_n, 0.0f);
        float lb   = fmaxf(ws[1] * inv_n * 0.25f, 0.0f);  // mean over 4N elems
        float lg   = fmaxf(ws[2] * inv_n, 0.0f);
        float lcut = fmaxf(ws[3] * inv_n, 0.0f);
        float total = 1.0f * lc + 5.0f * lb + 2.0f * lg + 3.0f * lcut;
        out[0] = total;
        out[1] = lc;
        out[2] = lb;
        out[3] = lg;
        out[4] = lcut;
    }
}

extern "C" void kernel_launch(void* const* d_in, const int* in_sizes, int n_in,
                              void* d_out, int out_size, void* d_ws, size_t ws_size,
                              hipStream_t stream) {
    const float4* pred_logits  = (const float4*)d_in[0];
    const int*    labels       = (const int*)d_in[1];
    const float4* pred_boxes   = (const float4*)d_in[2];
    const float4* target_boxes = (const float4*)d_in[3];
    const float*  cut_logits   = (const float*)d_in[4];
    const float*  cut_targets  = (const float*)d_in[5];
    float* ws  = (float*)d_ws;
    float* out = (float*)d_out;
    const int n = in_sizes[1];  // rows (labels element count)

    // ws is re-poisoned to 0xAA before every launch — zero the accumulators.
    hipMemsetAsync(d_ws, 0, 4 * sizeof(float), stream);

    const int block = 256;
    const int grid  = 4096;  // grid-stride: ~4 rows/thread at N=4.19M
    loss_reduce<<<grid, block, 0, stream>>>(pred_logits, labels, pred_boxes,
                                            target_boxes, cut_logits, cut_targets,
                                            ws, n);
    finalize_kernel<<<1, 64, 0, stream>>>(ws, out, 1.0f / (float)n);
}

// Round 2
// 245.038 us; speedup vs baseline: 1.6012x; 1.6012x over previous
//
#include <hip/hip_runtime.h>
#include <math.h>

#define EPS 1e-7f
#define FN_PENALTY 10.0f
#define BLOCK 256
#define ROWS_PER_THREAD 8

__device__ __forceinline__ float waveReduceSum(float v) {
    #pragma unroll
    for (int off = 32; off > 0; off >>= 1)
        v += __shfl_down(v, off, 64);
    return v;
}

__device__ __forceinline__ float4 validate_fix(float4 b) {
    bool invalid = (b.x > b.z) || (b.y > b.w);
    if (invalid) {
        b.x = fmaxf(b.x, 0.0f);
        b.y = fmaxf(b.y, 0.0f);
        b.z = fmaxf(b.z, 0.0f);
        b.w = fmaxf(b.w, 0.0f);
    }
    b.z = fmaxf(b.z, b.x + 1e-6f);
    b.w = fmaxf(b.w, b.y + 1e-6f);
    return b;
}

__device__ __forceinline__ void accum_row(
    float4 lg, int lbl, float4 pb, float4 tb, float cl, float ct,
    float& s_class, float& s_bbox, float& s_giou, float& s_cut)
{
    // ---- focal class loss ----
    float l0 = lg.x, l1 = lg.y, l2 = lg.z, l3 = lg.w;
    float m = fmaxf(fmaxf(l0, l1), fmaxf(l2, l3));
    float se = __expf(l0 - m) + __expf(l1 - m) + __expf(l2 - m) + __expf(l3 - m);
    float lse = m + __logf(se);
    lbl &= 3;
    float lsel = (lbl == 0) ? l0 : (lbl == 1) ? l1 : (lbl == 2) ? l2 : l3;
    float ce = lse - lsel;
    float pt = __expf(-ce);
    float om = 1.0f - pt;
    s_class += om * om * ce;   // ALPHA=1, GAMMA=2

    // ---- bbox L1 ----
    s_bbox += fabsf(pb.x - tb.x) + fabsf(pb.y - tb.y)
            + fabsf(pb.z - tb.z) + fabsf(pb.w - tb.w);

    // ---- GIoU ----
    float4 b1 = validate_fix(pb);
    float4 b2 = validate_fix(tb);
    float area1 = (b1.z - b1.x) * (b1.w - b1.y);
    float area2 = (b2.z - b2.x) * (b2.w - b2.y);
    float ltx = fmaxf(b1.x, b2.x), lty = fmaxf(b1.y, b2.y);
    float rbx = fminf(b1.z, b2.z), rby = fminf(b1.w, b2.w);
    float iw = fmaxf(rbx - ltx, 0.0f), ih = fmaxf(rby - lty, 0.0f);
    float inter = iw * ih;
    float uni = area1 + area2 - inter;
    float iou = inter / (uni + EPS);
    float ex1 = fminf(b1.x, b2.x), ey1 = fminf(b1.y, b2.y);
    float ex2 = fmaxf(b1.z, b2.z), ey2 = fmaxf(b1.w, b2.w);
    float ew = fmaxf(ex2 - ex1, 0.0f), eh = fmaxf(ey2 - ey1, 0.0f);
    float enc = ew * eh;
    float giou = iou - (enc - uni) / (enc + EPS);
    s_giou += fmaxf(1.0f - giou, 0.0f);

    // ---- weighted BCE ----
    float bce = fmaxf(cl, 0.0f) - cl * ct + log1pf(__expf(-fabsf(cl)));
    float prob = 1.0f / (1.0f + __expf(-cl));
    float w = ((ct == 1.0f) && (prob < 0.5f)) ? FN_PENALTY : 1.0f;
    s_cut += bce * w;
}

__global__ __launch_bounds__(BLOCK) void loss_reduce(
    const float4* __restrict__ pred_logits,
    const int*    __restrict__ labels,
    const float4* __restrict__ pred_boxes,
    const float4* __restrict__ target_boxes,
    const float*  __restrict__ cut_logits,
    const float*  __restrict__ cut_targets,
    float4* __restrict__ block_out, int n)
{
    float s_class = 0.0f, s_bbox = 0.0f, s_giou = 0.0f, s_cut = 0.0f;
    const int tid    = blockIdx.x * BLOCK + threadIdx.x;
    const int stride = gridDim.x * BLOCK;

    if (tid + (ROWS_PER_THREAD - 1) * stride < n && (long)stride * ROWS_PER_THREAD >= n) {
        // fast path: exactly ROWS_PER_THREAD rows per thread, fully unrolled.
        // All 48 loads issued up-front -> deep vmcnt pipeline.
        float4 lg[ROWS_PER_THREAD], pb[ROWS_PER_THREAD], tb[ROWS_PER_THREAD];
        int   lb[ROWS_PER_THREAD];
        float cl[ROWS_PER_THREAD], ct[ROWS_PER_THREAD];
        #pragma unroll
        for (int j = 0; j < ROWS_PER_THREAD; ++j) {
            int i = tid + j * stride;
            lg[j] = pred_logits[i];
            lb[j] = labels[i];
            pb[j] = pred_boxes[i];
            tb[j] = target_boxes[i];
            cl[j] = cut_logits[i];
            ct[j] = cut_targets[i];
        }
        #pragma unroll
        for (int j = 0; j < ROWS_PER_THREAD; ++j)
            accum_row(lg[j], lb[j], pb[j], tb[j], cl[j], ct[j],
                      s_class, s_bbox, s_giou, s_cut);
    } else {
        for (int i = tid; i < n; i += stride)
            accum_row(pred_logits[i], labels[i], pred_boxes[i], target_boxes[i],
                      cut_logits[i], cut_targets[i],
                      s_class, s_bbox, s_giou, s_cut);
    }

    // ---- block reduction: wave shuffle, then LDS across the 4 waves ----
    s_class = waveReduceSum(s_class);
    s_bbox  = waveReduceSum(s_bbox);
    s_giou  = waveReduceSum(s_giou);
    s_cut   = waveReduceSum(s_cut);

    __shared__ float red[4][4];
    const int lane = threadIdx.x & 63;
    const int wave = threadIdx.x >> 6;
    if (lane == 0) {
        red[wave][0] = s_class;
        red[wave][1] = s_bbox;
        red[wave][2] = s_giou;
        red[wave][3] = s_cut;
    }
    __syncthreads();
    if (threadIdx.x == 0) {
        float4 r;
        r.x = red[0][0] + red[1][0] + red[2][0] + red[3][0];
        r.y = red[0][1] + red[1][1] + red[2][1] + red[3][1];
        r.z = red[0][2] + red[1][2] + red[2][2] + red[3][2];
        r.w = red[0][3] + red[1][3] + red[2][3] + red[3][3];
        block_out[blockIdx.x] = r;   // per-block store: no atomics
    }
}

__global__ __launch_bounds__(BLOCK) void finalize_kernel(
    const float4* __restrict__ block_out, int nblocks,
    float* __restrict__ out, float inv_n)
{
    float c = 0.0f, b = 0.0f, g = 0.0f, u = 0.0f;
    for (int i = threadIdx.x; i < nblocks; i += BLOCK) {
        float4 r = block_out[i];
        c += r.x; b += r.y; g += r.z; u += r.w;
    }
    c = waveReduceSum(c);
    b = waveReduceSum(b);
    g = waveReduceSum(g);
    u = waveReduceSum(u);

    __shared__ float red[4][4];
    const int lane = threadIdx.x & 63;
    const int wave = threadIdx.x >> 6;
    if (lane == 0) {
        red[wave][0] = c; red[wave][1] = b; red[wave][2] = g; red[wave][3] = u;
    }
    __syncthreads();
    if (threadIdx.x == 0) {
        float sc = red[0][0] + red[1][0] + red[2][0] + red[3][0];
        float sb = red[0][1] + red[1][1] + red[2][1] + red[3][1];
        float sg = red[0][2] + red[1][2] + red[2][2] + red[3][2];
        float su = red[0][3] + red[1][3] + red[2][3] + red[3][3];
        float lc   = fmaxf(sc * inv_n, 0.0f);
        float lb   = fmaxf(sb * inv_n * 0.25f, 0.0f);
        float lg   = fmaxf(sg * inv_n, 0.0f);
        float lcut = fmaxf(su * inv_n, 0.0f);
        float total = 1.0f * lc + 5.0f * lb + 2.0f * lg + 3.0f * lcut;
        out[0] = total;
        out[1] = lc;
        out[2] = lb;
        out[3] = lg;
        out[4] = lcut;
    }
}

extern "C" void kernel_launch(void* const* d_in, const int* in_sizes, int n_in,
                              void* d_out, int out_size, void* d_ws, size_t ws_size,
                              hipStream_t stream) {
    const float4* pred_logits  = (const float4*)d_in[0];
    const int*    labels       = (const int*)d_in[1];
    const float4* pred_boxes   = (const float4*)d_in[2];
    const float4* target_boxes = (const float4*)d_in[3];
    const float*  cut_logits   = (const float*)d_in[4];
    const float*  cut_targets  = (const float*)d_in[5];
    float4* ws  = (float4*)d_ws;
    float*  out = (float*)d_out;
    const int n = in_sizes[1];  // rows

    // grid sized so each thread handles exactly ROWS_PER_THREAD rows when divisible
    int grid = (n + BLOCK * ROWS_PER_THREAD - 1) / (BLOCK * ROWS_PER_THREAD);
    if (grid < 1) grid = 1;

    loss_reduce<<<grid, BLOCK, 0, stream>>>(pred_logits, labels, pred_boxes,
                                            target_boxes, cut_logits, cut_targets,
                                            ws, n);
    finalize_kernel<<<1, BLOCK, 0, stream>>>(ws, grid, out, 1.0f / (float)n);
}

// Round 3
// 233.967 us; speedup vs baseline: 1.6770x; 1.0473x over previous
//
#include <hip/hip_runtime.h>
#include <math.h>

#define EPS 1e-7f
#define FN_PENALTY 10.0f
#define BLOCK 256

__device__ __forceinline__ float waveReduceSum(float v) {
    #pragma unroll
    for (int off = 32; off > 0; off >>= 1)
        v += __shfl_down(v, off, 64);
    return v;
}

__device__ __forceinline__ float4 validate_fix(float4 b) {
    bool invalid = (b.x > b.z) || (b.y > b.w);
    if (invalid) {
        b.x = fmaxf(b.x, 0.0f);
        b.y = fmaxf(b.y, 0.0f);
        b.z = fmaxf(b.z, 0.0f);
        b.w = fmaxf(b.w, 0.0f);
    }
    b.z = fmaxf(b.z, b.x + 1e-6f);
    b.w = fmaxf(b.w, b.y + 1e-6f);
    return b;
}

__device__ __forceinline__ void accum_row(
    float4 lg, int lbl, float4 pb, float4 tb, float cl, float ct,
    float& s_class, float& s_bbox, float& s_giou, float& s_cut)
{
    // ---- focal class loss ----
    float l0 = lg.x, l1 = lg.y, l2 = lg.z, l3 = lg.w;
    float m = fmaxf(fmaxf(l0, l1), fmaxf(l2, l3));
    float se = __expf(l0 - m) + __expf(l1 - m) + __expf(l2 - m) + __expf(l3 - m);
    float lse = m + __logf(se);
    lbl &= 3;
    float lsel = (lbl == 0) ? l0 : (lbl == 1) ? l1 : (lbl == 2) ? l2 : l3;
    float ce = lse - lsel;
    float pt = __expf(-ce);
    float om = 1.0f - pt;
    s_class += om * om * ce;   // ALPHA=1, GAMMA=2

    // ---- bbox L1 ----
    s_bbox += fabsf(pb.x - tb.x) + fabsf(pb.y - tb.y)
            + fabsf(pb.z - tb.z) + fabsf(pb.w - tb.w);

    // ---- GIoU ----
    float4 b1 = validate_fix(pb);
    float4 b2 = validate_fix(tb);
    float area1 = (b1.z - b1.x) * (b1.w - b1.y);
    float area2 = (b2.z - b2.x) * (b2.w - b2.y);
    float ltx = fmaxf(b1.x, b2.x), lty = fmaxf(b1.y, b2.y);
    float rbx = fminf(b1.z, b2.z), rby = fminf(b1.w, b2.w);
    float iw = fmaxf(rbx - ltx, 0.0f), ih = fmaxf(rby - lty, 0.0f);
    float inter = iw * ih;
    float uni = area1 + area2 - inter;
    float iou = inter / (uni + EPS);
    float ex1 = fminf(b1.x, b2.x), ey1 = fminf(b1.y, b2.y);
    float ex2 = fmaxf(b1.z, b2.z), ey2 = fmaxf(b1.w, b2.w);
    float ew = fmaxf(ex2 - ex1, 0.0f), eh = fmaxf(ey2 - ey1, 0.0f);
    float enc = ew * eh;
    float giou = iou - (enc - uni) / (enc + EPS);
    s_giou += fmaxf(1.0f - giou, 0.0f);

    // ---- weighted BCE ----
    // log1pf(exp(-|x|)) -> __logf(1+exp(-|x|)): abs err ~1e-7, fine vs 0.276 thr
    float bce = fmaxf(cl, 0.0f) - cl * ct + __logf(1.0f + __expf(-fabsf(cl)));
    // sigmoid(cl) < 0.5  <=>  cl < 0  (monotone) — saves an exp + rcp
    float w = ((ct == 1.0f) && (cl < 0.0f)) ? FN_PENALTY : 1.0f;
    s_cut += bce * w;
}

__device__ __forceinline__ void block_reduce_store(
    float s_class, float s_bbox, float s_giou, float s_cut,
    float4* __restrict__ out_slot)
{
    s_class = waveReduceSum(s_class);
    s_bbox  = waveReduceSum(s_bbox);
    s_giou  = waveReduceSum(s_giou);
    s_cut   = waveReduceSum(s_cut);

    __shared__ float red[4][4];
    const int lane = threadIdx.x & 63;
    const int wave = threadIdx.x >> 6;
    if (lane == 0) {
        red[wave][0] = s_class;
        red[wave][1] = s_bbox;
        red[wave][2] = s_giou;
        red[wave][3] = s_cut;
    }
    __syncthreads();
    if (threadIdx.x == 0) {
        float4 r;
        r.x = red[0][0] + red[1][0] + red[2][0] + red[3][0];
        r.y = red[0][1] + red[1][1] + red[2][1] + red[3][1];
        r.z = red[0][2] + red[1][2] + red[2][2] + red[3][2];
        r.w = red[0][3] + red[1][3] + red[2][3] + red[3][3];
        *out_slot = r;
    }
}

// Stage 1: one row per thread — copy-kernel shape (low VGPR, max TLP).
__global__ __launch_bounds__(BLOCK) void loss_reduce(
    const float4* __restrict__ pred_logits,
    const int*    __restrict__ labels,
    const float4* __restrict__ pred_boxes,
    const float4* __restrict__ target_boxes,
    const float*  __restrict__ cut_logits,
    const float*  __restrict__ cut_targets,
    float4* __restrict__ block_out, int n)
{
    const int i = blockIdx.x * BLOCK + threadIdx.x;
    float s_class = 0.0f, s_bbox = 0.0f, s_giou = 0.0f, s_cut = 0.0f;
    if (i < n) {
        accum_row(pred_logits[i], labels[i], pred_boxes[i], target_boxes[i],
                  cut_logits[i], cut_targets[i],
                  s_class, s_bbox, s_giou, s_cut);
    }
    block_reduce_store(s_class, s_bbox, s_giou, s_cut, &block_out[blockIdx.x]);
}

// Stage 2: reduce stage-1 partials (grid-stride, any count) -> gridDim partials.
__global__ __launch_bounds__(BLOCK) void reduce_partials(
    const float4* __restrict__ in, int n, float4* __restrict__ out)
{
    float c = 0.0f, b = 0.0f, g = 0.0f, u = 0.0f;
    for (int i = blockIdx.x * BLOCK + threadIdx.x; i < n; i += gridDim.x * BLOCK) {
        float4 r = in[i];
        c += r.x; b += r.y; g += r.z; u += r.w;
    }
    block_reduce_store(c, b, g, u, &out[blockIdx.x]);
}

// Stage 3: one wave reduces the 64 stage-2 partials and writes the 5 outputs.
__global__ void finalize_kernel(const float4* __restrict__ in, int n,
                                float* __restrict__ out, float inv_n)
{
    const int lane = threadIdx.x & 63;
    float c = 0.0f, b = 0.0f, g = 0.0f, u = 0.0f;
    for (int i = lane; i < n; i += 64) {
        float4 r = in[i];
        c += r.x; b += r.y; g += r.z; u += r.w;
    }
    c = waveReduceSum(c);
    b = waveReduceSum(b);
    g = waveReduceSum(g);
    u = waveReduceSum(u);
    if (lane == 0) {
        float lc   = fmaxf(c * inv_n, 0.0f);
        float lb   = fmaxf(b * inv_n * 0.25f, 0.0f);  // mean over 4N elems
        float lg   = fmaxf(g * inv_n, 0.0f);
        float lcut = fmaxf(u * inv_n, 0.0f);
        float total = 1.0f * lc + 5.0f * lb + 2.0f * lg + 3.0f * lcut;
        out[0] = total;
        out[1] = lc;
        out[2] = lb;
        out[3] = lg;
        out[4] = lcut;
    }
}

extern "C" void kernel_launch(void* const* d_in, const int* in_sizes, int n_in,
                              void* d_out, int out_size, void* d_ws, size_t ws_size,
                              hipStream_t stream) {
    const float4* pred_logits  = (const float4*)d_in[0];
    const int*    labels       = (const int*)d_in[1];
    const float4* pred_boxes   = (const float4*)d_in[2];
    const float4* target_boxes = (const float4*)d_in[3];
    const float*  cut_logits   = (const float*)d_in[4];
    const float*  cut_targets  = (const float*)d_in[5];
    float4* ws4 = (float4*)d_ws;
    float*  out = (float*)d_out;
    const int n = in_sizes[1];  // rows

    const int grid1 = (n + BLOCK - 1) / BLOCK;      // 16384 @ N=4.19M
    const int grid2 = 64;
    float4* part1 = ws4;                            // grid1 entries (256 KB)
    float4* part2 = ws4 + grid1;                    // grid2 entries (1 KB)

    loss_reduce<<<grid1, BLOCK, 0, stream>>>(pred_logits, labels, pred_boxes,
                                             target_boxes, cut_logits, cut_targets,
                                             part1, n);
    reduce_partials<<<grid2, BLOCK, 0, stream>>>(part1, grid1, part2);
    finalize_kernel<<<1, 64, 0, stream>>>(part2, grid2, out, 1.0f / (float)n);
}